// Round 1
// baseline (184.077 us; speedup 1.0000x reference)
//
#include <hip/hip_runtime.h>

// Problem constants (match reference file)
#define KK   3
#define Bn   8
#define Cn   64
#define Hn   128
#define Wn   128
#define HoN  128
#define WoN  128
#define NTAP 9

__global__ __launch_bounds__(256) void dyn_unfold_kernel(
    const float* __restrict__ x,      // (B, C, H, W)
    const float* __restrict__ dmap,   // (B, 1, Ho, Wo)
    float* __restrict__ out)          // (B, C*9, Ho*Wo)
{
    int tid = blockIdx.x * blockDim.x + threadIdx.x;
    // tid -> (b, t, oh, ow), ow fastest for coalescing
    int ow  = tid & (WoN - 1);
    int tmp = tid >> 7;               // / WoN
    int oh  = tmp & (HoN - 1);
    tmp >>= 7;                        // / HoN
    int t   = tmp % NTAP;
    int b   = tmp / NTAP;
    if (b >= Bn) return;
    int ki = t / KK;
    int kj = t % KK;

    // dilation multiplier for this output pixel
    float d = dmap[(b * HoN + oh) * WoN + ow];

    // sample position (stride=1, pad=1, dil=1)
    float R  = (float)(oh - 1) + (float)ki * d;
    float Cc = (float)(ow - 1) + (float)kj * d;

    float r0f = floorf(R);
    float c0f = floorf(Cc);
    float wr = R - r0f;
    float wc = Cc - c0f;
    int r0 = (int)r0f;
    int c0 = (int)c0f;
    int r1 = r0 + 1;
    int c1 = c0 + 1;

    // validity folded into weights (identical algebra to reference's mask-mul)
    float vr0 = (r0 >= 0 && r0 < Hn) ? 1.0f : 0.0f;
    float vr1 = (r1 >= 0 && r1 < Hn) ? 1.0f : 0.0f;
    float vc0 = (c0 >= 0 && c0 < Wn) ? 1.0f : 0.0f;
    float vc1 = (c1 >= 0 && c1 < Wn) ? 1.0f : 0.0f;

    int r0c = min(max(r0, 0), Hn - 1);
    int r1c = min(max(r1, 0), Hn - 1);
    int c0c = min(max(c0, 0), Wn - 1);
    int c1c = min(max(c1, 0), Wn - 1);

    float w00 = (1.0f - wr) * (1.0f - wc) * vr0 * vc0;
    float w01 = (1.0f - wr) * wc          * vr0 * vc1;
    float w10 = wr          * (1.0f - wc) * vr1 * vc0;
    float w11 = wr          * wc          * vr1 * vc1;

    // channel-invariant corner offsets
    int o00 = r0c * Wn + c0c;
    int o01 = r0c * Wn + c1c;
    int o10 = r1c * Wn + c0c;
    int o11 = r1c * Wn + c1c;

    const float* __restrict__ xb = x + (size_t)b * Cn * Hn * Wn;
    float* __restrict__ ob = out + ((size_t)b * (Cn * NTAP) + t) * (HoN * WoN)
                                 + oh * WoN + ow;

    const size_t ostride = (size_t)NTAP * HoN * WoN;  // between channels in out

    #pragma unroll 4
    for (int c = 0; c < Cn; ++c) {
        const float* __restrict__ p = xb + (size_t)c * Hn * Wn;
        float v = w00 * p[o00] + w01 * p[o01] + w10 * p[o10] + w11 * p[o11];
        ob[(size_t)c * ostride] = v;
    }
}

extern "C" void kernel_launch(void* const* d_in, const int* in_sizes, int n_in,
                              void* d_out, int out_size, void* d_ws, size_t ws_size,
                              hipStream_t stream) {
    const float* x    = (const float*)d_in[0];
    const float* dmap = (const float*)d_in[1];
    float* out = (float*)d_out;

    const int total = Bn * NTAP * HoN * WoN;       // 1,179,648 threads
    const int block = 256;
    const int grid  = (total + block - 1) / block; // 4608 blocks
    dyn_unfold_kernel<<<grid, block, 0, stream>>>(x, dmap, out);
}

// Round 2
// 178.856 us; speedup vs baseline: 1.0292x; 1.0292x over previous
//
#include <hip/hip_runtime.h>

// Problem constants (match reference file)
#define KK   3
#define Bn   8
#define Cn   64
#define Hn   128
#define Wn   128
#define HoN  128
#define WoN  128
#define NTAP 9

__global__ __launch_bounds__(256) void dyn_unfold_kernel(
    const float* __restrict__ x,      // (B, C, H, W)
    const float* __restrict__ dmap,   // (B, 1, Ho, Wo)
    float* __restrict__ out)          // (B, C*9, Ho*Wo)
{
    int tid = blockIdx.x * blockDim.x + threadIdx.x;
    // tid -> (b, t, oh, ow), ow fastest for coalescing
    int ow  = tid & (WoN - 1);
    int tmp = tid >> 7;               // / WoN
    int oh  = tmp & (HoN - 1);
    tmp >>= 7;                        // / HoN
    int t   = tmp % NTAP;
    int b   = tmp / NTAP;
    if (b >= Bn) return;
    int ki = t / KK;
    int kj = t % KK;

    // dilation multiplier for this output pixel
    float d = dmap[(b * HoN + oh) * WoN + ow];

    // sample position (stride=1, pad=1, dil=1)
    float R  = (float)(oh - 1) + (float)ki * d;
    float Cc = (float)(ow - 1) + (float)kj * d;

    float r0f = floorf(R);
    float c0f = floorf(Cc);
    float wr = R - r0f;
    float wc = Cc - c0f;
    int r0 = (int)r0f;
    int c0 = (int)c0f;
    int r1 = r0 + 1;
    int c1 = c0 + 1;

    // validity folded into weights (identical algebra to reference's mask-mul)
    float vr0 = (r0 >= 0 && r0 < Hn) ? 1.0f : 0.0f;
    float vr1 = (r1 >= 0 && r1 < Hn) ? 1.0f : 0.0f;
    float vc0 = (c0 >= 0 && c0 < Wn) ? 1.0f : 0.0f;
    float vc1 = (c1 >= 0 && c1 < Wn) ? 1.0f : 0.0f;

    int r0c = min(max(r0, 0), Hn - 1);
    int r1c = min(max(r1, 0), Hn - 1);
    int c0c = min(max(c0, 0), Wn - 1);
    int c1c = min(max(c1, 0), Wn - 1);

    float w00 = (1.0f - wr) * (1.0f - wc) * vr0 * vc0;
    float w01 = (1.0f - wr) * wc          * vr0 * vc1;
    float w10 = wr          * (1.0f - wc) * vr1 * vc0;
    float w11 = wr          * wc          * vr1 * vc1;

    // channel-invariant corner offsets
    int o00 = r0c * Wn + c0c;
    int o01 = r0c * Wn + c1c;
    int o10 = r1c * Wn + c0c;
    int o11 = r1c * Wn + c1c;

    const float* __restrict__ xb = x + (size_t)b * Cn * Hn * Wn;
    float* __restrict__ ob = out + ((size_t)b * (Cn * NTAP) + t) * (HoN * WoN)
                                 + oh * WoN + ow;

    const size_t ostride = (size_t)NTAP * HoN * WoN;  // between channels in out
    const int    plane   = Hn * Wn;                    // floats between channels in x

    // Chunked channel loop: batch 64 gather loads (16 ch x 4 corners) into
    // registers BEFORE any use -> ~64 outstanding VMEM per wave (was ~16).
    #pragma unroll
    for (int cc = 0; cc < Cn; cc += 16) {
        float a00[16], a01[16], a10[16], a11[16];
        #pragma unroll
        for (int u = 0; u < 16; ++u) {
            const float* __restrict__ p = xb + (size_t)(cc + u) * plane;
            a00[u] = p[o00];
            a01[u] = p[o01];
            a10[u] = p[o10];
            a11[u] = p[o11];
        }
        #pragma unroll
        for (int u = 0; u < 16; ++u) {
            float v = w00 * a00[u] + w01 * a01[u] + w10 * a10[u] + w11 * a11[u];
            // streaming store: out is never re-read -> keep L2 for x gathers
            __builtin_nontemporal_store(v, ob + (size_t)(cc + u) * ostride);
        }
    }
}

extern "C" void kernel_launch(void* const* d_in, const int* in_sizes, int n_in,
                              void* d_out, int out_size, void* d_ws, size_t ws_size,
                              hipStream_t stream) {
    const float* x    = (const float*)d_in[0];
    const float* dmap = (const float*)d_in[1];
    float* out = (float*)d_out;

    const int total = Bn * NTAP * HoN * WoN;       // 1,179,648 threads
    const int block = 256;
    const int grid  = (total + block - 1) / block; // 4608 blocks
    dyn_unfold_kernel<<<grid, block, 0, stream>>>(x, dmap, out);
}

// Round 3
// 71.281 us; speedup vs baseline: 2.5824x; 2.5092x over previous
//
#include <hip/hip_runtime.h>

// Problem constants (match reference file)
#define KK   3
#define Bn   8
#define Cn   64
#define Hn   128
#define Wn   128
#define NTAP 9

// Blocking
#define BAND  8                 // output rows per block
#define CHB   4                 // channels per block
#define ROWS  15                // BAND-1 + floor(2*3.0) + 1 (bilinear r1)
#define NBANDS (Hn / BAND)      // 16
#define NCG    (Cn / CHB)       // 16

__global__ __launch_bounds__(256) void dyn_unfold_kernel(
    const float* __restrict__ x,      // (B, C, H, W)
    const float* __restrict__ dmap,   // (B, 1, H, W)
    float* __restrict__ out)          // (B, C*9, H*W)
{
    __shared__ float lds[CHB][ROWS][Wn];   // 4*15*128*4B = 30 KB

    const int bid  = blockIdx.x;
    const int cg   = bid & (NCG - 1);          // channel group (fastest)
    const int band = (bid >> 4) & (NBANDS - 1);
    const int b    = bid >> 8;

    const int oh0 = band * BAND;
    const int tid = threadIdx.x;

    // ---- stage input rows [oh0-1, oh0+13] (row-clamped) for CHB channels ----
    const float* __restrict__ xb = x + ((size_t)b * Cn + cg * CHB) * (Hn * Wn);
    const int NF4 = CHB * ROWS * (Wn / 4);     // 1920 float4
    for (int f = tid; f < NF4; f += 256) {
        int ch  = f / (ROWS * (Wn / 4));
        int rem = f % (ROWS * (Wn / 4));
        int row = rem / (Wn / 4);
        int c4  = rem % (Wn / 4);
        int ih  = oh0 - 1 + row;
        ih = min(max(ih, 0), Hn - 1);          // clamped rows; weights mask them
        float4 v = *reinterpret_cast<const float4*>(
            xb + ((size_t)ch * Hn + ih) * Wn + c4 * 4);
        *reinterpret_cast<float4*>(&lds[ch][row][c4 * 4]) = v;
    }
    __syncthreads();

    // ---- compute: 4 pixels/thread x 9 taps x CHB channels ----
    #pragma unroll
    for (int px = 0; px < 4; ++px) {
        const int p    = tid + px * 256;
        const int oh_l = p >> 7;               // 0..7
        const int ow   = p & (Wn - 1);
        const int oh   = oh0 + oh_l;

        const float d = dmap[((size_t)b * Hn + oh) * Wn + ow];

        #pragma unroll
        for (int t = 0; t < NTAP; ++t) {
            const int ki = t / KK;
            const int kj = t % KK;

            float R  = (float)(oh - 1) + (float)ki * d;
            float Cc = (float)(ow - 1) + (float)kj * d;

            float r0f = floorf(R);
            float c0f = floorf(Cc);
            float wr = R - r0f;
            float wc = Cc - c0f;
            int r0 = (int)r0f;
            int c0 = (int)c0f;
            int r1 = r0 + 1;
            int c1 = c0 + 1;

            float vr0 = (r0 >= 0 && r0 < Hn) ? 1.0f : 0.0f;
            float vr1 = (r1 >= 0 && r1 < Hn) ? 1.0f : 0.0f;
            float vc0 = (c0 >= 0 && c0 < Wn) ? 1.0f : 0.0f;
            float vc1 = (c1 >= 0 && c1 < Wn) ? 1.0f : 0.0f;

            int r0c = min(max(r0, 0), Hn - 1);
            int r1c = min(max(r1, 0), Hn - 1);
            int c0c = min(max(c0, 0), Wn - 1);
            int c1c = min(max(c1, 0), Wn - 1);

            float w00 = (1.0f - wr) * (1.0f - wc) * vr0 * vc0;
            float w01 = (1.0f - wr) * wc          * vr0 * vc1;
            float w10 = wr          * (1.0f - wc) * vr1 * vc0;
            float w11 = wr          * wc          * vr1 * vc1;

            // LDS-local row indices (staged range starts at oh0-1)
            const int l0 = r0c - oh0 + 1;      // in [0, 14]
            const int l1 = r1c - oh0 + 1;      // in [0, 14]

            #pragma unroll
            for (int ch = 0; ch < CHB; ++ch) {
                float v = w00 * lds[ch][l0][c0c] + w01 * lds[ch][l0][c1c]
                        + w10 * lds[ch][l1][c0c] + w11 * lds[ch][l1][c1c];
                float* dst = out
                    + ((size_t)b * Cn * NTAP + (size_t)(cg * CHB + ch) * NTAP + t)
                        * (size_t)(Hn * Wn)
                    + (size_t)oh * Wn + ow;
                __builtin_nontemporal_store(v, dst);
            }
        }
    }
}

extern "C" void kernel_launch(void* const* d_in, const int* in_sizes, int n_in,
                              void* d_out, int out_size, void* d_ws, size_t ws_size,
                              hipStream_t stream) {
    const float* x    = (const float*)d_in[0];
    const float* dmap = (const float*)d_in[1];
    float* out = (float*)d_out;

    const int grid  = Bn * NBANDS * NCG;   // 8*16*16 = 2048 blocks
    const int block = 256;
    dyn_unfold_kernel<<<grid, block, 0, stream>>>(x, dmap, out);
}